// Round 10
// baseline (439.679 us; speedup 1.0000x reference)
//
#include <hip/hip_runtime.h>
#include <hip/hip_bf16.h>
#include <math.h>
#include <stdint.h>

typedef __bf16 bf16_t;
typedef __attribute__((ext_vector_type(8))) __bf16 bf16x8;
typedef __attribute__((ext_vector_type(4))) float f32x4;
typedef float f32x4a __attribute__((ext_vector_type(4), aligned(4)));
typedef unsigned short u16;
typedef unsigned int u32;

#define DEV static __device__ __forceinline__
#define LOG2E 1.4426950408889634f

DEV u16 f2b(float f){ bf16_t h = (bf16_t)f; return __builtin_bit_cast(u16, h); }
DEV float b2f(u16 u){ bf16_t h = __builtin_bit_cast(bf16_t, u); return (float)h; }
DEV f32x4 mfma16(bf16x8 a, bf16x8 b, f32x4 c){
  return __builtin_amdgcn_mfma_f32_16x16x32_bf16(a, b, c, 0, 0, 0);
}

#if __has_builtin(__builtin_amdgcn_exp2f)
DEV float fexp2(float x){ return __builtin_amdgcn_exp2f(x); }
#else
DEV float fexp2(float x){ return exp2f(x); }
#endif

DEV void gld16(const void* g, void* l){
  __builtin_amdgcn_global_load_lds((const __attribute__((address_space(1))) u32*)g,
                                   (__attribute__((address_space(3))) u32*)l, 16, 0, 0);
}

DEV bf16x8 ldsA64(const u16* arr, int row, int ch){
  return *(const bf16x8*)&arr[row*64 + ((ch ^ (row&7))*8)];
}
DEV bf16x8 ldsA32(const u16* arr, int row, int ch){
  return *(const bf16x8*)&arr[row*32 + ((ch ^ ((row>>1)&3))*8)];
}

// ---------------- merged prep: convert_x (blocks 0..4095) + convert_w (4096..5119) + bias_table (5120..5375) ----------------
__global__ __launch_bounds__(256) void k_prep(const float* __restrict__ x,
                                              const float* __restrict__ Wq, const float* __restrict__ Wk,
                                              const float* __restrict__ Wv, const float* __restrict__ Wo,
                                              const float* __restrict__ rel_table, const float* __restrict__ mask,
                                              u16* __restrict__ xh, u16* __restrict__ xl,
                                              u16* __restrict__ wth, u16* __restrict__ wot,
                                              float* __restrict__ bt, float* __restrict__ bt2,
                                              float* __restrict__ msk2){
  __shared__ float tile[64][65];
  int bid = blockIdx.x;
  int t = threadIdx.x;
  if(bid < 4096){
    size_t i = ((size_t)bid*256 + t)*4;
    float4 v = *(const float4*)(x + i);
    ushort4 hv, lv; float f, hf;
    f=v.x; hv.x=f2b(f); hf=b2f(hv.x); lv.x=f2b(f-hf);
    f=v.y; hv.y=f2b(f); hf=b2f(hv.y); lv.y=f2b(f-hf);
    f=v.z; hv.z=f2b(f); hf=b2f(hv.z); lv.z=f2b(f-hf);
    f=v.w; hv.w=f2b(f); hf=b2f(hv.w); lv.w=f2b(f-hf);
    *(ushort4*)(xh+i) = hv;
    *(ushort4*)(xl+i) = lv;
  } else if(bid < 5120){
    int rr = bid - 4096;
    int z = rr >> 8, ky = (rr >> 4) & 15, nx = rr & 15;
    const float* W = (z==0)?Wq:((z==1)?Wk:((z==2)?Wv:Wo));
    int n0 = nx*64, k0 = ky*64;
    int r = t>>6, c = t&63;
    #pragma unroll
    for(int i=0;i<16;i++){
      int row = i*4 + r;
      tile[row][c] = W[(size_t)(k0+row)*1024 + n0 + c];
    }
    __syncthreads();
    #pragma unroll
    for(int i=0;i<16;i++){
      int nrow = i*4 + r;
      float v = tile[c][nrow];
      size_t o = (size_t)(n0+nrow)*1024 + k0 + c;
      if(z<3) wth[(size_t)z*1048576 + o] = f2b(v);
      else    wot[o] = f2b(v);
    }
  } else {
    int gid = (bid-5120)*256 + t;   // 16*4096
    if(gid < 4096) msk2[gid] = mask[gid]*LOG2E;
    int h = gid >> 12, idx = gid & 4095;
    float v = 0.f;
    if(idx < 4095){
      int delta = idx - 2047;   // k - q
      int n = -delta;
      int ret = 0;
      if(n < 0){ ret = 16; n = -n; }
      int bucket;
      if(n < 8) bucket = n + ret;
      else {
        float a = (float)log((double)n * 0.125);
        float rr2 = (float)((double)a / (double)2.7725887298583984f);
        int vl = 8 + (int)(rr2 * 8.0f);
        vl = vl > 15 ? 15 : vl;
        bucket = vl + ret;
      }
      v = rel_table[bucket*16 + h];
    }
    bt[gid] = v;
    bt2[gid] = v*LOG2E - 32.0f;
  }
}

// ---------------- QKV projection GEMM — load-balanced 4-slice grid (R9) ----------------
__global__ __launch_bounds__(256) void k_gemm_qkv(const u16* __restrict__ xh, const u16* __restrict__ xl,
                                                  const u16* __restrict__ wth,
                                                  u16* __restrict__ qh, u16* __restrict__ ql,
                                                  u16* __restrict__ kh, u16* __restrict__ vt){
  __shared__ __align__(16) u16 SM[20480];
  int zp = blockIdx.z;
  int lin2 = blockIdx.x + 8*blockIdx.y;          // [0,256)
  int nl2 = (lin2 & 7)*32 + (lin2 >> 3);         // bijective XCD swizzle: 256 = 8*32
  int m0 = (nl2 >> 3)*128;
  int t = threadIdx.x, w = t>>6, lane = t&63, l16 = lane&15, g = lane>>4;
  int rbase = (w>>1)*64;

  if(zp < 2){
    // ---- Q path: 128 x 64 tile, 2-term ----
    int n0 = zp*512 + (nl2 & 7)*64;
    const u16* WH = wth;   // Wq
    int cbase = (w&1)*32;
    f32x4 acc[4][2];
    #pragma unroll
    for(int i=0;i<4;i++)
      #pragma unroll
      for(int j=0;j<2;j++) acc[i][j] = {0.f,0.f,0.f,0.f};

    #pragma unroll
    for(int jj=0;jj<5;jj++){
      int q = w + 4*jj;
      int arr = q>>3, sub = q&7;
      int row = sub*16 + (lane>>2);
      int lch = (lane&3) ^ ((row>>1)&3);
      const u16* src;
      if(arr==0)      src = xh + (size_t)(m0+row)*1024 + lch*8;
      else if(arr==1) src = xl + (size_t)(m0+row)*1024 + lch*8;
      else            src = WH + (size_t)(n0+row)*1024 + lch*8;
      gld16(src, &SM[q*512]);
    }
    __syncthreads();

    for(int it=0; it<32; ++it){
      const u16* Ah = SM + (it&1)*10240;
      const u16* Al = Ah + 4096;
      const u16* Bh = Ah + 8192;
      if(it < 31){
        u16* dstb = SM + ((it+1)&1)*10240;
        int kn = (it+1)*32;
        #pragma unroll
        for(int jj=0;jj<5;jj++){
          int q = w + 4*jj;
          int arr = q>>3, sub = q&7;
          int row = sub*16 + (lane>>2);
          int lch = (lane&3) ^ ((row>>1)&3);
          const u16* src;
          if(arr==0)      src = xh + (size_t)(m0+row)*1024 + kn + lch*8;
          else if(arr==1) src = xl + (size_t)(m0+row)*1024 + kn + lch*8;
          else            src = WH + (size_t)(n0+row)*1024 + kn + lch*8;
          gld16(src, dstb + q*512);
        }
        __builtin_amdgcn_sched_barrier(0);
      }
      bf16x8 ah[4], am[4];
      #pragma unroll
      for(int i=0;i<4;i++){
        int row = rbase + i*16 + l16;
        ah[i] = ldsA32(Ah, row, g);
        am[i] = ldsA32(Al, row, g);
      }
      #pragma unroll
      for(int j=0;j<2;j++){
        bf16x8 bh = ldsA32(Bh, cbase + j*16 + l16, g);
        #pragma unroll
        for(int i=0;i<4;i++){
          acc[i][j] = mfma16(ah[i], bh, acc[i][j]);
          acc[i][j] = mfma16(am[i], bh, acc[i][j]);
        }
      }
      __syncthreads();
    }
    #pragma unroll
    for(int i=0;i<4;i++)
      #pragma unroll
      for(int j=0;j<2;j++)
        #pragma unroll
        for(int r=0;r<4;r++){
          int m = m0 + rbase + i*16 + g*4 + r;
          int n = n0 + cbase + j*16 + l16;
          float v = acc[i][j][r] * LOG2E;
          int b = m >> 11, s = m & 2047;
          int hh = n >> 6, d = n & 63;
          size_t a = ((size_t)(b*16+hh)*2048 + s)*64 + d;
          u16 hb = f2b(v);
          qh[a] = hb;
          ql[a] = f2b(v - b2f(hb));
        }
  } else {
    // ---- K/V path: 128 x 128 tile, 1-term ----
    int z = zp - 1;                                // 1=K, 2=V
    int n0 = (nl2 & 7)*128;
    const u16* WH = wth + (size_t)z*1048576;
    int cbase = (w&1)*64;
    f32x4 acc[4][4];
    #pragma unroll
    for(int i=0;i<4;i++)
      #pragma unroll
      for(int j=0;j<4;j++) acc[i][j] = {0.f,0.f,0.f,0.f};

    #pragma unroll
    for(int jj=0;jj<4;jj++){
      int q = w + 4*jj;
      int arr = q>>3, sub = q&7;
      int row = sub*16 + (lane>>2);
      int lch = (lane&3) ^ ((row>>1)&3);
      const u16* src = (arr==0) ? xh + (size_t)(m0+row)*1024 + lch*8
                                : WH + (size_t)(n0+row)*1024 + lch*8;
      gld16(src, &SM[q*512]);
    }
    __syncthreads();

    for(int it=0; it<32; ++it){
      const u16* As = SM + (it&1)*8192;
      const u16* Bs = As + 4096;
      if(it < 31){
        u16* dstb = SM + ((it+1)&1)*8192;
        int kn = (it+1)*32;
        #pragma unroll
        for(int jj=0;jj<4;jj++){
          int q = w + 4*jj;
          int arr = q>>3, sub = q&7;
          int row = sub*16 + (lane>>2);
          int lch = (lane&3) ^ ((row>>1)&3);
          const u16* src = (arr==0) ? xh + (size_t)(m0+row)*1024 + kn + lch*8
                                    : WH + (size_t)(n0+row)*1024 + kn + lch*8;
          gld16(src, dstb + q*512);
        }
        __builtin_amdgcn_sched_barrier(0);
      }
      bf16x8 ah[4];
      #pragma unroll
      for(int i=0;i<4;i++) ah[i] = ldsA32(As, rbase + i*16 + l16, g);
      #pragma unroll
      for(int j=0;j<4;j++){
        bf16x8 bh = ldsA32(Bs, cbase + j*16 + l16, g);
        #pragma unroll
        for(int i=0;i<4;i++)
          acc[i][j] = mfma16(ah[i], bh, acc[i][j]);
      }
      __syncthreads();
    }
    if(z==2){
      // V: transpose via LDS (stride 136), coalesced stores; vt [bh][d][s]
      #pragma unroll
      for(int i=0;i<4;i++)
        #pragma unroll
        for(int j=0;j<4;j++)
          #pragma unroll
          for(int r=0;r<4;r++){
            int ml = rbase + i*16 + g*4 + r;
            int nl = cbase + j*16 + l16;
            SM[nl*136 + ml] = f2b(acc[i][j][r]);
          }
      __syncthreads();
      int bb = m0 >> 11;
      #pragma unroll
      for(int kk=0;kk<8;kk++){
        int id = t + 256*kk;
        int row = id>>4, ch = id&15;
        uint4 v = *(const uint4*)&SM[row*136 + ch*8];
        int n = n0 + row;
        size_t dst = ((size_t)(bb*16 + (n>>6))*64 + (n&63))*2048 + (m0&2047) + ch*8;
        *(uint4*)&vt[dst] = v;
      }
    } else {
      #pragma unroll
      for(int i=0;i<4;i++)
        #pragma unroll
        for(int j=0;j<4;j++)
          #pragma unroll
          for(int r=0;r<4;r++){
            int m = m0 + rbase + i*16 + g*4 + r;
            int n = n0 + cbase + j*16 + l16;
            int b = m >> 11, s = m & 2047;
            int hh = n >> 6, d = n & 63;
            size_t a = ((size_t)(b*16+hh)*2048 + s)*64 + d;
            kh[a] = f2b(acc[i][j][r]);
          }
    }
  }
}

// ---------------- flash attention + distributed position_bias write ----------------
// R8's 2x2 (q,k) wave split, now at launch_bounds(256,3): ~170 VGPR budget -> no spills.
// wave(wr=w>>1, wc=w&1) owns 32 q-rows x 32 k. K reads 8->4, V reads 8->4 per wave-iter.
// Occupancy 3 blocks/CU (12 waves) vs R7's 4 — A/B isolates LDS-issue-bound vs latency-bound.
// LDS: 2x(KH 8KB|VT 8KB) + PS 4x2KB = 40KB.
__global__ __launch_bounds__(256,3) void k_attn(const u16* __restrict__ qh, const u16* __restrict__ ql,
                                              const u16* __restrict__ kh,
                                              const u16* __restrict__ vt, const float* __restrict__ bt2,
                                              const float* __restrict__ msk2,
                                              const float* __restrict__ bt, float* __restrict__ bias_out,
                                              u16* __restrict__ ao){
  __shared__ __align__(16) u16 SM[20480];
  int lin = blockIdx.x + 32*blockIdx.y;          // [0,1024)
  int nlw = (lin & 7)*128 + (lin >> 3);          // bijective: 1024 = 8*128
  int qx = nlw & 31, bh = nlw >> 5;
  int b = bh>>4, h = bh&15;
  int q0 = qx*64;
  int t = threadIdx.x, w = t>>6, lane = t&63, l16 = lane&15, g = lane>>4;
  int wr = w>>1, wc = w&1;
  size_t base  = (size_t)bh*2048*64;   // q/k: [bh][s][64]
  size_t vbase = (size_t)bh*64*2048;   // v^T: [bh][d][s]
  u16* PSq = SM + 16384 + w*1024;      // wave-private 32x32 (stride 32), XOR-swizzled
  const float* bt2h = bt2 + h*4096;
  const float* msk2b = msk2 + b*2048;
  size_t wbase = ((size_t)(bh*32 + qx))*65536 + t*8;   // this block's bias_out slice

  // register-resident Q (pre-scaled by log2e): wave owns q-rows q0+wr*32+jq*16+l16
  bf16x8 qfh[2][2], qfl[2][2];
  #pragma unroll
  for(int jq=0;jq<2;jq++){
    int qr = q0 + wr*32 + jq*16 + l16;
    size_t a0 = base + (size_t)qr*64 + g*8;
    qfh[jq][0] = *(const bf16x8*)&qh[a0];
    qfl[jq][0] = *(const bf16x8*)&ql[a0];
    qfh[jq][1] = *(const bf16x8*)&qh[a0+32];
    qfl[jq][1] = *(const bf16x8*)&ql[a0+32];
  }
  f32x4 O[2][4];
  float rsw[2] = {0.f, 0.f};
  #pragma unroll
  for(int jq=0;jq<2;jq++)
    #pragma unroll
    for(int jd=0;jd<4;jd++) O[jq][jd] = {0.f,0.f,0.f,0.f};

  // prologue: stage tile 0 into buf0, publish
  #pragma unroll
  for(int jj=0;jj<4;jj++){
    int q = w + 4*jj;
    int arr = q>>3, sub = q&7;
    int row = sub*8 + (lane>>3);
    int lch = (lane&7) ^ (row&7);
    const u16* src = (arr==0) ? kh + base + (size_t)row*64 + lch*8
                              : vt + vbase + (size_t)row*2048 + lch*8;
    gld16(src, &SM[q*512]);
  }
  __syncthreads();

  for(int it=0; it<32; ++it){
    int k0 = it*64;
    const u16* KH = SM + (it&1)*8192;
    const u16* VT = KH + 4096;
    // issue next-tile stage into the other buffer (drained by this iter's closing barrier)
    if(it < 31){
      u16* dstb = SM + ((it+1)&1)*8192;
      int kn = k0 + 64;
      #pragma unroll
      for(int jj=0;jj<4;jj++){
        int q = w + 4*jj;
        int arr = q>>3, sub = q&7;
        int row = sub*8 + (lane>>3);
        int lch = (lane&7) ^ (row&7);
        const u16* src = (arr==0) ? kh + base + (size_t)(kn+row)*64 + lch*8
                                  : vt + vbase + (size_t)row*2048 + kn + lch*8;
        gld16(src, dstb + q*512);
      }
      __builtin_amdgcn_sched_barrier(0);
    }
    // distributed bias_out write: gather from L2-hot bt, nt stores retire under compute
    {
      size_t f = wbase + (size_t)it*2048;
      int hh = (int)(f >> 22);
      int rem = (int)(f & 4194303);
      int qq = rem >> 11;
      int kk = rem & 2047;
      const float* row = bt + hh*4096 + (kk - qq + 2047);
      f32x4a v0 = *(const f32x4a*)(row);
      f32x4a v1 = *(const f32x4a*)(row + 4);
      __builtin_nontemporal_store(v0, (f32x4a*)(bias_out + f));
      __builtin_nontemporal_store(v1, (f32x4a*)(bias_out + f + 4));
    }
    // C-init: sc[jq][j][r] for k = k0+wc*32+j*16+g*4+r, q = q0+wr*32+jq*16+l16
    f32x4 sc[2][2];
    {
      int kb = k0 + wc*32 + g*4;
      const float* mm = msk2b + kb;
      const float* bb = bt2h + (kb + 2047 - (q0 + wr*32 + l16));
      #pragma unroll
      for(int jq=0;jq<2;jq++)
        #pragma unroll
        for(int j=0;j<2;j++){
          f32x4a bvv = *(const f32x4a*)(bb + j*16 - jq*16);
          f32x4a mvv = *(const f32x4a*)(mm + j*16);
          sc[jq][j] = (f32x4){bvv[0]+mvv[0], bvv[1]+mvv[1], bvv[2]+mvv[2], bvv[3]+mvv[3]};
        }
    }
    // QK^T swapped (A=K rows, B=Q rows): wave's k-half only (4 K reads, each feeds 4 MFMA)
    __builtin_amdgcn_s_setprio(1);
    #pragma unroll
    for(int j=0;j<2;j++){
      int krow = wc*32 + j*16 + l16;
      bf16x8 kfh0 = ldsA64(KH, krow, g);
      bf16x8 kfh1 = ldsA64(KH, krow, 4+g);
      #pragma unroll
      for(int jq=0;jq<2;jq++){
        f32x4 s = sc[jq][j];
        s = mfma16(kfh0, qfh[jq][0], s);
        s = mfma16(kfh0, qfl[jq][0], s);
        s = mfma16(kfh1, qfh[jq][1], s);
        s = mfma16(kfh1, qfl[jq][1], s);
        sc[jq][j] = s;
      }
    }
    __builtin_amdgcn_s_setprio(0);
    // exp2, accumulate partial row-sum (q = jq*16+l16, wave's k-half), packed b64 P writes
    #pragma unroll
    for(int jq=0;jq<2;jq++)
      #pragma unroll
      for(int j=0;j<2;j++){
        float p0 = fexp2(sc[jq][j][0]);
        float p1 = fexp2(sc[jq][j][1]);
        float p2 = fexp2(sc[jq][j][2]);
        float p3 = fexp2(sc[jq][j][3]);
        rsw[jq] += (p0+p1) + (p2+p3);
        ushort4 us = { f2b(p0), f2b(p1), f2b(p2), f2b(p3) };
        int rowp = jq*16 + l16;
        int c8 = j*2 + (g>>1);
        *(ushort4*)&PSq[rowp*32 + ((c8 ^ ((rowp>>1)&3))*8) + (g&1)*4] = us;
      }
    // PV over wave's k-half: 4 shared V reads (each feeds 2 MFMA) + 2 pa reads
    __builtin_amdgcn_s_setprio(1);
    {
      bf16x8 vbh[4];
      #pragma unroll
      for(int jd=0;jd<4;jd++) vbh[jd] = ldsA64(VT, jd*16 + l16, wc*4 + g);
      #pragma unroll
      for(int jq=0;jq<2;jq++){
        bf16x8 pa = ldsA32(PSq, jq*16 + l16, g);
        #pragma unroll
        for(int jd=0;jd<4;jd++)
          O[jq][jd] = mfma16(pa, vbh[jd], O[jq][jd]);
      }
    }
    __builtin_amdgcn_s_setprio(0);
    __syncthreads();   // vmcnt(0)+lgkmcnt(0)+barrier: publish stage(t+1) to all waves
  }

  // epilogue: combine k-halves. wc=1 publishes O-partials (16KB, swizzled) + rs (PS area);
  // wc=0 adds, g-reduces row-sums, normalizes, stores.
  float* Of = (float*)SM;
  if(wc == 1){
    #pragma unroll
    for(int jq=0;jq<2;jq++)
      #pragma unroll
      for(int jd=0;jd<4;jd++){
        int c = jq*4 + jd;
        *(f32x4*)&Of[wr*2048 + lane*32 + ((c ^ (lane&7))*4)] = O[jq][jd];
      }
    float* rsf = (float*)&SM[16384 + w*1024];
    rsf[lane] = rsw[0];
    rsf[64+lane] = rsw[1];
  }
  __syncthreads();
  if(wc == 0){
    float* rsf = (float*)&SM[16384 + (w+1)*1024];
    float tot0 = rsw[0] + rsf[lane];
    float tot1 = rsw[1] + rsf[64+lane];
    tot0 += __shfl_xor(tot0, 16, 64);
    tot0 += __shfl_xor(tot0, 32, 64);
    tot1 += __shfl_xor(tot1, 16, 64);
    tot1 += __shfl_xor(tot1, 32, 64);
    #pragma unroll
    for(int jq=0;jq<2;jq++)
      #pragma unroll
      for(int jd=0;jd<4;jd++){
        int c = jq*4 + jd;
        f32x4 part = *(const f32x4*)&Of[wr*2048 + lane*32 + ((c ^ (lane&7))*4)];
        O[jq][jd] += part;
      }
    #pragma unroll
    for(int jq=0;jq<2;jq++){
      float tj = (jq==0) ? tot0 : tot1;
      #pragma unroll
      for(int r=0;r<4;r++){
        float inv = 1.f/__shfl(tj, g*4+r, 64);
        int q = q0 + wr*32 + jq*16 + g*4 + r;
        size_t a = ((size_t)(b*2048 + q))*1024 + h*64;
        #pragma unroll
        for(int jd=0;jd<4;jd++)
          ao[a + jd*16 + l16] = f2b(O[jq][jd][r]*inv);
      }
    }
  }
}

// ---------------- output projection ----------------
// Retiled 128x64 (grid 512 = 2 blocks/CU). T3-minimum double-buffered K-loop.
__global__ __launch_bounds__(256) void k_gemm_out(const u16* __restrict__ ao, const u16* __restrict__ wot,
                                                  float* __restrict__ out){
  __shared__ __align__(16) u16 SM[12288];
  int lin2 = blockIdx.x + 16*blockIdx.y;         // [0,512)
  int nl2 = (lin2 & 7)*64 + (lin2 >> 3);         // bijective: 512 = 8*64
  int n0 = (nl2 & 15)*64, m0 = (nl2 >> 4)*128;
  int t = threadIdx.x, w = t>>6, lane = t&63, l16 = lane&15, g = lane>>4;
  f32x4 acc[4][2];
  #pragma unroll
  for(int i=0;i<4;i++)
    #pragma unroll
    for(int j=0;j<2;j++) acc[i][j] = {0.f,0.f,0.f,0.f};
  int rbase = (w>>1)*64, cbase = (w&1)*32;

  // prologue: stage tile 0 into buf0 (A 8 chunks + B 4 chunks, 3 per wave), publish
  #pragma unroll
  for(int jj=0;jj<3;jj++){
    int q = w + 4*jj;
    int arr = q>>3, sub = q&7;
    int row = sub*16 + (lane>>2);
    int lch = (lane&3) ^ ((row>>1)&3);
    const u16* src = (arr==0) ? ao  + (size_t)(m0+row)*1024 + lch*8
                              : wot + (size_t)(n0+row)*1024 + lch*8;
    gld16(src, &SM[q*512]);
  }
  __syncthreads();

  for(int it=0; it<32; ++it){
    const u16* As = SM + (it&1)*6144;
    const u16* Bs = As + 4096;
    if(it < 31){
      u16* dstb = SM + ((it+1)&1)*6144;
      int kn = (it+1)*32;
      #pragma unroll
      for(int jj=0;jj<3;jj++){
        int q = w + 4*jj;
        int arr = q>>3, sub = q&7;
        int row = sub*16 + (lane>>2);
        int lch = (lane&3) ^ ((row>>1)&3);
        const u16* src = (arr==0) ? ao  + (size_t)(m0+row)*1024 + kn + lch*8
                                  : wot + (size_t)(n0+row)*1024 + kn + lch*8;
        gld16(src, dstb + q*512);
      }
      __builtin_amdgcn_sched_barrier(0);
    }
    bf16x8 af[4];
    #pragma unroll
    for(int i=0;i<4;i++) af[i] = ldsA32(As, rbase + i*16 + l16, g);
    #pragma unroll
    for(int j=0;j<2;j++){
      bf16x8 bfb = ldsA32(Bs, cbase + j*16 + l16, g);
      #pragma unroll
      for(int i=0;i<4;i++)
        acc[i][j] = mfma16(af[i], bfb, acc[i][j]);
    }
    __syncthreads();
  }
  #pragma unroll
  for(int i=0;i<4;i++)
    #pragma unroll
    for(int j=0;j<2;j++)
      #pragma unroll
      for(int r=0;r<4;r++){
        int m = m0 + rbase + i*16 + g*4 + r;
        int n = n0 + cbase + j*16 + l16;
        __builtin_nontemporal_store(acc[i][j][r], &out[(size_t)m*1024 + n]);
      }
}

// ---------------- launch ----------------
extern "C" void kernel_launch(void* const* d_in, const int* in_sizes, int n_in,
                              void* d_out, int out_size, void* d_ws, size_t ws_size,
                              hipStream_t stream) {
  const float* x   = (const float*)d_in[0];
  const float* Wq  = (const float*)d_in[1];
  const float* Wk  = (const float*)d_in[2];
  const float* Wv  = (const float*)d_in[3];
  const float* Wo  = (const float*)d_in[4];
  const float* rel = (const float*)d_in[5];
  const float* msk = (const float*)d_in[6];
  float* out = (float*)d_out;
  float* bias_out = out + (size_t)4194304;
  char* ws = (char*)d_ws;
  u16* xh  = (u16*)(ws + 0);              // 8 MB
  u16* xl  = (u16*)(ws + 8388608);        // 8 MB
  u16* wth = (u16*)(ws + 16777216);       // 6 MB
  u16* wot = (u16*)(ws + 23068672);       // 2 MB
  u16* qh  = (u16*)(ws + 25165824);       // 8 MB
  u16* ql  = (u16*)(ws + 33554432);       // 8 MB
  u16* kh  = (u16*)(ws + 41943040);       // 8 MB
  u16* vt  = (u16*)(ws + 50331648);       // 8 MB (32 x 64 x 2048)
  u16* ao  = (u16*)(ws + 58720256);       // 8 MB
  float* bt  = (float*)(ws + 67108864);   // 256 KB
  float* bt2 = (float*)(ws + 67371008);   // 256 KB
  float* msk2= (float*)(ws + 67633152);   // 16 KB

  k_prep      <<<5376, 256, 0, stream>>>(x, Wq, Wk, Wv, Wo, rel, msk,
                                         xh, xl, wth, wot, bt, bt2, msk2);
  k_gemm_qkv  <<<dim3(8,32,4), 256, 0, stream>>>(xh, xl, wth, qh, ql, kh, vt);
  k_attn      <<<dim3(32,32), 256, 0, stream>>>(qh, ql, kh, vt, bt2, msk2, bt, bias_out, ao);
  k_gemm_out  <<<dim3(16,32), 256, 0, stream>>>(ao, wot, out);
}

// Round 11
// 435.789 us; speedup vs baseline: 1.0089x; 1.0089x over previous
//
#include <hip/hip_runtime.h>
#include <hip/hip_bf16.h>
#include <math.h>
#include <stdint.h>

typedef __bf16 bf16_t;
typedef __attribute__((ext_vector_type(8))) __bf16 bf16x8;
typedef __attribute__((ext_vector_type(4))) float f32x4;
typedef float f32x4a __attribute__((ext_vector_type(4), aligned(4)));
typedef unsigned short u16;
typedef unsigned int u32;

#define DEV static __device__ __forceinline__
#define LOG2E 1.4426950408889634f

DEV u16 f2b(float f){ bf16_t h = (bf16_t)f; return __builtin_bit_cast(u16, h); }
DEV float b2f(u16 u){ bf16_t h = __builtin_bit_cast(bf16_t, u); return (float)h; }
DEV f32x4 mfma16(bf16x8 a, bf16x8 b, f32x4 c){
  return __builtin_amdgcn_mfma_f32_16x16x32_bf16(a, b, c, 0, 0, 0);
}

#if __has_builtin(__builtin_amdgcn_exp2f)
DEV float fexp2(float x){ return __builtin_amdgcn_exp2f(x); }
#else
DEV float fexp2(float x){ return exp2f(x); }
#endif

DEV void gld16(const void* g, void* l){
  __builtin_amdgcn_global_load_lds((const __attribute__((address_space(1))) u32*)g,
                                   (__attribute__((address_space(3))) u32*)l, 16, 0, 0);
}

DEV bf16x8 ldsA64(const u16* arr, int row, int ch){
  return *(const bf16x8*)&arr[row*64 + ((ch ^ (row&7))*8)];
}
DEV bf16x8 ldsA32(const u16* arr, int row, int ch){
  return *(const bf16x8*)&arr[row*32 + ((ch ^ ((row>>1)&3))*8)];
}

// ---------------- merged prep: convert_x (blocks 0..4095) + convert_w (4096..5119) + bias_table (5120..5375) ----------------
__global__ __launch_bounds__(256) void k_prep(const float* __restrict__ x,
                                              const float* __restrict__ Wq, const float* __restrict__ Wk,
                                              const float* __restrict__ Wv, const float* __restrict__ Wo,
                                              const float* __restrict__ rel_table, const float* __restrict__ mask,
                                              u16* __restrict__ xh, u16* __restrict__ xl,
                                              u16* __restrict__ wth, u16* __restrict__ wot,
                                              float* __restrict__ bt, float* __restrict__ bt2,
                                              float* __restrict__ msk2){
  __shared__ float tile[64][65];
  int bid = blockIdx.x;
  int t = threadIdx.x;
  if(bid < 4096){
    size_t i = ((size_t)bid*256 + t)*4;
    float4 v = *(const float4*)(x + i);
    ushort4 hv, lv; float f, hf;
    f=v.x; hv.x=f2b(f); hf=b2f(hv.x); lv.x=f2b(f-hf);
    f=v.y; hv.y=f2b(f); hf=b2f(hv.y); lv.y=f2b(f-hf);
    f=v.z; hv.z=f2b(f); hf=b2f(hv.z); lv.z=f2b(f-hf);
    f=v.w; hv.w=f2b(f); hf=b2f(hv.w); lv.w=f2b(f-hf);
    *(ushort4*)(xh+i) = hv;
    *(ushort4*)(xl+i) = lv;
  } else if(bid < 5120){
    int rr = bid - 4096;
    int z = rr >> 8, ky = (rr >> 4) & 15, nx = rr & 15;
    const float* W = (z==0)?Wq:((z==1)?Wk:((z==2)?Wv:Wo));
    int n0 = nx*64, k0 = ky*64;
    int r = t>>6, c = t&63;
    #pragma unroll
    for(int i=0;i<16;i++){
      int row = i*4 + r;
      tile[row][c] = W[(size_t)(k0+row)*1024 + n0 + c];
    }
    __syncthreads();
    #pragma unroll
    for(int i=0;i<16;i++){
      int nrow = i*4 + r;
      float v = tile[c][nrow];
      size_t o = (size_t)(n0+nrow)*1024 + k0 + c;
      if(z<3) wth[(size_t)z*1048576 + o] = f2b(v);
      else    wot[o] = f2b(v);
    }
  } else {
    int gid = (bid-5120)*256 + t;   // 16*4096
    if(gid < 4096) msk2[gid] = mask[gid]*LOG2E;
    int h = gid >> 12, idx = gid & 4095;
    float v = 0.f;
    if(idx < 4095){
      int delta = idx - 2047;   // k - q
      int n = -delta;
      int ret = 0;
      if(n < 0){ ret = 16; n = -n; }
      int bucket;
      if(n < 8) bucket = n + ret;
      else {
        float a = (float)log((double)n * 0.125);
        float rr2 = (float)((double)a / (double)2.7725887298583984f);
        int vl = 8 + (int)(rr2 * 8.0f);
        vl = vl > 15 ? 15 : vl;
        bucket = vl + ret;
      }
      v = rel_table[bucket*16 + h];
    }
    bt[gid] = v;
    bt2[gid] = v*LOG2E - 32.0f;
  }
}

// ---------------- QKV projection GEMM ----------------
// Q: 2-term ((xh+xl)*Wh); K,V: 1-term (xh*Wh). XCD-chunked swizzle.
// T3-minimum double-buffered loop: stage(t+1) -> compute(t) -> __syncthreads().
__global__ __launch_bounds__(256) void k_gemm_qkv(const u16* __restrict__ xh, const u16* __restrict__ xl,
                                                  const u16* __restrict__ wth,
                                                  u16* __restrict__ qh, u16* __restrict__ ql,
                                                  u16* __restrict__ kh, u16* __restrict__ vt){
  __shared__ __align__(16) u16 SM[24576];
  int z = blockIdx.z;
  const u16* WH = wth + (size_t)z*1048576;
  int lin2 = blockIdx.x + 8*blockIdx.y;          // [0,256)
  int nl2 = (lin2 & 7)*32 + (lin2 >> 3);         // bijective: 256 = 8*32
  int n0 = (nl2 & 7)*128, m0 = (nl2 >> 3)*128;
  int t = threadIdx.x, w = t>>6, lane = t&63, l16 = lane&15, g = lane>>4;
  f32x4 acc[4][4];
  #pragma unroll
  for(int i=0;i<4;i++)
    #pragma unroll
    for(int j=0;j<4;j++) acc[i][j] = {0.f,0.f,0.f,0.f};
  int rbase = (w>>1)*64, cbase = (w&1)*64;

  // prologue: stage tile 0 into buf0, publish
  #pragma unroll
  for(int jj=0;jj<6;jj++){
    int q = w + 4*jj;
    int arr = q>>3, sub = q&7;
    if(z!=0 && arr==1) continue;
    int row = sub*16 + (lane>>2);
    int lch = (lane&3) ^ ((row>>1)&3);
    const u16* src;
    if(arr==0)      src = xh + (size_t)(m0+row)*1024 + lch*8;
    else if(arr==1) src = xl + (size_t)(m0+row)*1024 + lch*8;
    else            src = WH + (size_t)(n0+row)*1024 + lch*8;
    gld16(src, &SM[q*512]);
  }
  __syncthreads();

  for(int it=0; it<32; ++it){
    const u16* Ah = SM + (it&1)*12288;
    const u16* Al = Ah + 4096;
    const u16* Bh = Ah + 8192;
    // issue next-tile stage into the other buffer (drained by this iter's closing barrier)
    if(it < 31){
      u16* dstb = SM + ((it+1)&1)*12288;
      int kn = (it+1)*32;
      #pragma unroll
      for(int jj=0;jj<6;jj++){
        int q = w + 4*jj;
        int arr = q>>3, sub = q&7;
        if(z!=0 && arr==1) continue;
        int row = sub*16 + (lane>>2);
        int lch = (lane&3) ^ ((row>>1)&3);
        const u16* src;
        if(arr==0)      src = xh + (size_t)(m0+row)*1024 + kn + lch*8;
        else if(arr==1) src = xl + (size_t)(m0+row)*1024 + kn + lch*8;
        else            src = WH + (size_t)(n0+row)*1024 + kn + lch*8;
        gld16(src, dstb + q*512);
      }
      __builtin_amdgcn_sched_barrier(0);
    }
    // compute(t) on buf[it&1]
    if(z!=0){
      bf16x8 ah[4];
      #pragma unroll
      for(int i=0;i<4;i++) ah[i] = ldsA32(Ah, rbase + i*16 + l16, g);
      #pragma unroll
      for(int j=0;j<4;j++){
        bf16x8 bh = ldsA32(Bh, cbase + j*16 + l16, g);
        #pragma unroll
        for(int i=0;i<4;i++)
          acc[i][j] = mfma16(ah[i], bh, acc[i][j]);
      }
    } else {
      bf16x8 ah[4], am[4];
      #pragma unroll
      for(int i=0;i<4;i++){
        int row = rbase + i*16 + l16;
        ah[i] = ldsA32(Ah, row, g);
        am[i] = ldsA32(Al, row, g);
      }
      #pragma unroll
      for(int j=0;j<4;j++){
        bf16x8 bh = ldsA32(Bh, cbase + j*16 + l16, g);
        #pragma unroll
        for(int i=0;i<4;i++){
          acc[i][j] = mfma16(ah[i], bh, acc[i][j]);
          acc[i][j] = mfma16(am[i], bh, acc[i][j]);
        }
      }
    }
    __syncthreads();   // vmcnt(0)+lgkmcnt(0)+barrier: publish stage(t+1) to all waves
  }
  if(z==2){
    // V: transpose via LDS (stride 136), coalesced 16B stores; vt [bh][d][s]
    #pragma unroll
    for(int i=0;i<4;i++)
      #pragma unroll
      for(int j=0;j<4;j++)
        #pragma unroll
        for(int r=0;r<4;r++){
          int ml = rbase + i*16 + g*4 + r;
          int nl = cbase + j*16 + l16;
          SM[nl*136 + ml] = f2b(acc[i][j][r]);
        }
    __syncthreads();
    int bb = m0 >> 11;
    #pragma unroll
    for(int kk=0;kk<8;kk++){
      int id = t + 256*kk;
      int row = id>>4, ch = id&15;
      uint4 v = *(const uint4*)&SM[row*136 + ch*8];
      int n = n0 + row;
      size_t dst = ((size_t)(bb*16 + (n>>6))*64 + (n&63))*2048 + (m0&2047) + ch*8;
      *(uint4*)&vt[dst] = v;
    }
  } else {
    #pragma unroll
    for(int i=0;i<4;i++)
      #pragma unroll
      for(int j=0;j<4;j++)
        #pragma unroll
        for(int r=0;r<4;r++){
          int m = m0 + rbase + i*16 + g*4 + r;
          int n = n0 + cbase + j*16 + l16;
          float v = acc[i][j][r];
          if(z==0) v *= LOG2E;
          int b = m >> 11, s = m & 2047;
          int hh = n >> 6, d = n & 63;
          size_t a = ((size_t)(b*16+hh)*2048 + s)*64 + d;
          u16 hb = f2b(v);
          if(z==0){ qh[a]=hb; ql[a]=f2b(v - b2f(hb)); }
          else    { kh[a]=hb; }
        }
  }
}

// ---------------- flash attention + distributed position_bias write (R7-best) ----------------
// dbuf, 1 barrier/iter, 4 blocks/CU + SWAPPED QK^T: s = mfma(K, Q, C)
// -> C col=q(l16), row=k(g*4+r): each lane's 16 P values are one q-row, r-consecutive k.
//   P writes: 4 ds_write_b64 (ushort4, chunk c=j*2+(g>>1), half g&1, XOR-swz matches ldsA64).
//   C-init: r-increasing (no reversal), mask as aligned f32x4. Row-sum: scalar/lane.
// LDS: 2x(KH 8KB|VT 8KB) + PS 4x[16][64]swz = 40KB -> 4 blocks/CU.
__global__ __launch_bounds__(256,4) void k_attn(const u16* __restrict__ qh, const u16* __restrict__ ql,
                                              const u16* __restrict__ kh,
                                              const u16* __restrict__ vt, const float* __restrict__ bt2,
                                              const float* __restrict__ msk2,
                                              const float* __restrict__ bt, float* __restrict__ bias_out,
                                              u16* __restrict__ ao){
  __shared__ __align__(16) u16 SM[20480];
  int lin = blockIdx.x + 32*blockIdx.y;          // [0,1024)
  int nlw = (lin & 7)*128 + (lin >> 3);          // bijective: 1024 = 8*128
  int qx = nlw & 31, bh = nlw >> 5;
  int b = bh>>4, h = bh&15;
  int q0 = qx*64;
  int t = threadIdx.x, w = t>>6, lane = t&63, l16 = lane&15, g = lane>>4;
  size_t base  = (size_t)bh*2048*64;   // q/k: [bh][s][64]
  size_t vbase = (size_t)bh*64*2048;   // v^T: [bh][d][s]
  u16* PSw = SM + 16384 + w*1024;      // [16][64] chunk-XOR-swizzled, wave-private
  const float* bt2h = bt2 + h*4096;
  const float* msk2b = msk2 + b*2048;
  size_t wbase = ((size_t)(bh*32 + qx))*65536 + t*8;   // this block's bias_out slice

  // register-resident Q (pre-scaled by log2e): wave w owns q-rows q0+w*16..+15
  bf16x8 qfh[2], qfl[2];
  {
    int qr = q0 + w*16 + l16;
    size_t a0 = base + (size_t)qr*64 + g*8;
    qfh[0] = *(const bf16x8*)&qh[a0];
    qfl[0] = *(const bf16x8*)&ql[a0];
    qfh[1] = *(const bf16x8*)&qh[a0+32];
    qfl[1] = *(const bf16x8*)&ql[a0+32];
  }
  f32x4 O[4];
  float rs4[4];
  #pragma unroll
  for(int jd=0;jd<4;jd++) O[jd] = {0.f,0.f,0.f,0.f};
  #pragma unroll
  for(int r=0;r<4;r++) rs4[r] = 0.f;
  int qgbase = q0 + w*16 + g*4;

  // prologue: gather bias values for iter 0
  f32x4a bv0, bv1;
  {
    size_t f = wbase;
    int hh = (int)(f >> 22);
    int rem = (int)(f & 4194303);
    int qq = rem >> 11;
    int kk = rem & 2047;
    const float* row = bt + hh*4096 + (kk - qq + 2047);
    bv0 = *(const f32x4a*)(row);
    bv1 = *(const f32x4a*)(row + 4);
  }
  // prologue: stage tile 0 into buf0, publish
  #pragma unroll
  for(int jj=0;jj<4;jj++){
    int q = w + 4*jj;
    int arr = q>>3, sub = q&7;
    int row = sub*8 + (lane>>3);
    int lch = (lane&7) ^ (row&7);
    const u16* src = (arr==0) ? kh + base + (size_t)row*64 + lch*8
                              : vt + vbase + (size_t)row*2048 + lch*8;
    gld16(src, &SM[q*512]);
  }
  __syncthreads();

  for(int it=0; it<32; ++it){
    int k0 = it*64;
    const u16* KH = SM + (it&1)*8192;
    const u16* VT = KH + 4096;
    // issue next-tile stage into the other buffer (drained by this iter's closing barrier)
    if(it < 31){
      u16* dstb = SM + ((it+1)&1)*8192;
      int kn = k0 + 64;
      #pragma unroll
      for(int jj=0;jj<4;jj++){
        int q = w + 4*jj;
        int arr = q>>3, sub = q&7;
        int row = sub*8 + (lane>>3);
        int lch = (lane&7) ^ (row&7);
        const u16* src = (arr==0) ? kh + base + (size_t)(kn+row)*64 + lch*8
                                  : vt + vbase + (size_t)row*2048 + kn + lch*8;
        gld16(src, dstb + q*512);
      }
      __builtin_amdgcn_sched_barrier(0);
    }
    // C-init: sc[j][r] for k = k0+j*16+g*4+r, q = q0+w*16+l16 (r-increasing, no reversal)
    f32x4 sc[4];
    {
      const float* bb = bt2h + (k0 + g*4 + 2047 - (q0 + w*16 + l16));
      const float* mm = msk2b + k0 + g*4;
      #pragma unroll
      for(int j=0;j<4;j++){
        f32x4a bvv = *(const f32x4a*)(bb + j*16);
        f32x4a mvv = *(const f32x4a*)(mm + j*16);
        sc[j] = (f32x4){bvv[0]+mvv[0], bvv[1]+mvv[1], bvv[2]+mvv[2], bvv[3]+mvv[3]};
      }
    }
    // distributed bias_out write: prefetched data, non-temporal; retires under compute
    {
      size_t f = wbase + (size_t)it*2048;
      __builtin_nontemporal_store(bv0, (f32x4a*)(bias_out + f));
      __builtin_nontemporal_store(bv1, (f32x4a*)(bias_out + f + 4));
      if(it < 31){
        size_t fn = f + 2048;
        int hh = (int)(fn >> 22);
        int rem = (int)(fn & 4194303);
        int qq = rem >> 11;
        int kk = rem & 2047;
        const float* row = bt + hh*4096 + (kk - qq + 2047);
        bv0 = *(const f32x4a*)(row);
        bv1 = *(const f32x4a*)(row + 4);
      }
    }
    // QK^T SWAPPED: A=K rows, B=Q rows -> C col=q(l16), row=k(g*4+r)
    __builtin_amdgcn_s_setprio(1);
    #pragma unroll
    for(int j=0;j<4;j++){
      int krow = j*16 + l16;
      bf16x8 kfh0 = ldsA64(KH, krow, g);
      bf16x8 kfh1 = ldsA64(KH, krow, 4+g);
      f32x4 s = sc[j];
      s = mfma16(kfh0, qfh[0], s);
      s = mfma16(kfh0, qfl[0], s);
      s = mfma16(kfh1, qfh[1], s);
      s = mfma16(kfh1, qfl[1], s);
      sc[j] = s;
    }
    __builtin_amdgcn_s_setprio(0);
    // exp2, accumulate row-sum (lane-local q=l16), packed b64 P writes
    #pragma unroll
    for(int j=0;j<4;j++){
      float p0 = fexp2(sc[j][0]); rs4[0] += p0;
      float p1 = fexp2(sc[j][1]); rs4[1] += p1;
      float p2 = fexp2(sc[j][2]); rs4[2] += p2;
      float p3 = fexp2(sc[j][3]); rs4[3] += p3;
      ushort4 us = { f2b(p0), f2b(p1), f2b(p2), f2b(p3) };
      int ch = (j*2 + (g>>1)) ^ (l16 & 7);
      *(ushort4*)&PSw[l16*64 + ch*8 + (g&1)*4] = us;
    }
    // PV (PS is wave-private, no barrier) — pa read: chunk k=ds*32+g*8..+7
    __builtin_amdgcn_s_setprio(1);
    #pragma unroll
    for(int ds=0; ds<2; ds++){
      bf16x8 pa = ldsA64(PSw, l16, ds*4 + g);
      #pragma unroll
      for(int jd=0;jd<4;jd++){
        bf16x8 vb = ldsA64(VT, jd*16 + l16, ds*4 + g);
        O[jd] = mfma16(pa, vb, O[jd]);
      }
    }
    __builtin_amdgcn_s_setprio(0);
    __syncthreads();   // vmcnt(0)+lgkmcnt(0)+barrier: publish stage(t+1) to all waves
  }
  // epilogue: lane holds partial row-sum for q=l16; reduce over g, redistribute, normalize
  float tot = (rs4[0]+rs4[1]) + (rs4[2]+rs4[3]);
  tot += __shfl_xor(tot, 16, 64);
  tot += __shfl_xor(tot, 32, 64);
  #pragma unroll
  for(int r=0;r<4;r++){
    float inv = 1.f/__shfl(tot, g*4+r, 64);
    int q = qgbase + r;
    size_t a = ((size_t)(b*2048 + q))*1024 + h*64;
    #pragma unroll
    for(int jd=0;jd<4;jd++)
      ao[a + jd*16 + l16] = f2b(O[jd][r]*inv);
  }
}

// ---------------- output projection ----------------
// Retiled 128x64 (grid 512 = 2 blocks/CU). T3-minimum double-buffered K-loop.
__global__ __launch_bounds__(256) void k_gemm_out(const u16* __restrict__ ao, const u16* __restrict__ wot,
                                                  float* __restrict__ out){
  __shared__ __align__(16) u16 SM[12288];
  int lin2 = blockIdx.x + 16*blockIdx.y;         // [0,512)
  int nl2 = (lin2 & 7)*64 + (lin2 >> 3);         // bijective: 512 = 8*64
  int n0 = (nl2 & 15)*64, m0 = (nl2 >> 4)*128;
  int t = threadIdx.x, w = t>>6, lane = t&63, l16 = lane&15, g = lane>>4;
  f32x4 acc[4][2];
  #pragma unroll
  for(int i=0;i<4;i++)
    #pragma unroll
    for(int j=0;j<2;j++) acc[i][j] = {0.f,0.f,0.f,0.f};
  int rbase = (w>>1)*64, cbase = (w&1)*32;

  // prologue: stage tile 0 into buf0 (A 8 chunks + B 4 chunks, 3 per wave), publish
  #pragma unroll
  for(int jj=0;jj<3;jj++){
    int q = w + 4*jj;
    int arr = q>>3, sub = q&7;
    int row = sub*16 + (lane>>2);
    int lch = (lane&3) ^ ((row>>1)&3);
    const u16* src = (arr==0) ? ao  + (size_t)(m0+row)*1024 + lch*8
                              : wot + (size_t)(n0+row)*1024 + lch*8;
    gld16(src, &SM[q*512]);
  }
  __syncthreads();

  for(int it=0; it<32; ++it){
    const u16* As = SM + (it&1)*6144;
    const u16* Bs = As + 4096;
    if(it < 31){
      u16* dstb = SM + ((it+1)&1)*6144;
      int kn = (it+1)*32;
      #pragma unroll
      for(int jj=0;jj<3;jj++){
        int q = w + 4*jj;
        int arr = q>>3, sub = q&7;
        int row = sub*16 + (lane>>2);
        int lch = (lane&3) ^ ((row>>1)&3);
        const u16* src = (arr==0) ? ao  + (size_t)(m0+row)*1024 + kn + lch*8
                                  : wot + (size_t)(n0+row)*1024 + kn + lch*8;
        gld16(src, dstb + q*512);
      }
      __builtin_amdgcn_sched_barrier(0);
    }
    bf16x8 af[4];
    #pragma unroll
    for(int i=0;i<4;i++) af[i] = ldsA32(As, rbase + i*16 + l16, g);
    #pragma unroll
    for(int j=0;j<2;j++){
      bf16x8 bfb = ldsA32(Bs, cbase + j*16 + l16, g);
      #pragma unroll
      for(int i=0;i<4;i++)
        acc[i][j] = mfma16(af[i], bfb, acc[i][j]);
    }
    __syncthreads();
  }
  #pragma unroll
  for(int i=0;i<4;i++)
    #pragma unroll
    for(int j=0;j<2;j++)
      #pragma unroll
      for(int r=0;r<4;r++){
        int m = m0 + rbase + i*16 + g*4 + r;
        int n = n0 + cbase + j*16 + l16;
        __builtin_nontemporal_store(acc[i][j][r], &out[(size_t)m*1024 + n]);
      }
}

// ---------------- launch ----------------
extern "C" void kernel_launch(void* const* d_in, const int* in_sizes, int n_in,
                              void* d_out, int out_size, void* d_ws, size_t ws_size,
                              hipStream_t stream) {
  const float* x   = (const float*)d_in[0];
  const float* Wq  = (const float*)d_in[1];
  const float* Wk  = (const float*)d_in[2];
  const float* Wv  = (const float*)d_in[3];
  const float* Wo  = (const float*)d_in[4];
  const float* rel = (const float*)d_in[5];
  const float* msk = (const float*)d_in[6];
  float* out = (float*)d_out;
  float* bias_out = out + (size_t)4194304;
  char* ws = (char*)d_ws;
  u16* xh  = (u16*)(ws + 0);              // 8 MB
  u16* xl  = (u16*)(ws + 8388608);        // 8 MB
  u16* wth = (u16*)(ws + 16777216);       // 6 MB
  u16* wot = (u16*)(ws + 23068672);       // 2 MB
  u16* qh  = (u16*)(ws + 25165824);       // 8 MB
  u16* ql  = (u16*)(ws + 33554432);       // 8 MB
  u16* kh  = (u16*)(ws + 41943040);       // 8 MB
  u16* vt  = (u16*)(ws + 50331648);       // 8 MB (32 x 64 x 2048)
  u16* ao  = (u16*)(ws + 58720256);       // 8 MB
  float* bt  = (float*)(ws + 67108864);   // 256 KB
  float* bt2 = (float*)(ws + 67371008);   // 256 KB
  float* msk2= (float*)(ws + 67633152);   // 16 KB

  k_prep      <<<5376, 256, 0, stream>>>(x, Wq, Wk, Wv, Wo, rel, msk,
                                         xh, xl, wth, wot, bt, bt2, msk2);
  k_gemm_qkv  <<<dim3(8,32,3), 256, 0, stream>>>(xh, xl, wth, qh, ql, kh, vt);
  k_attn      <<<dim3(32,32), 256, 0, stream>>>(qh, ql, kh, vt, bt2, msk2, bt, bias_out, ao);
  k_gemm_out  <<<dim3(16,32), 256, 0, stream>>>(ao, wot, out);
}